// Round 1
// baseline (1041.532 us; speedup 1.0000x reference)
//
#include <hip/hip_runtime.h>
#include <cstdint>
#include <cstddef>

// Problem constants
#define Bv   2
#define Sv   2048
#define Dv   1024
#define Hv   16
#define DEP  64
#define BHv  32          // B*H
#define MROWS 4096       // B*S

typedef float    f32x4 __attribute__((ext_vector_type(4)));
typedef float    f32x2 __attribute__((ext_vector_type(2)));
typedef _Float16 f16x8 __attribute__((ext_vector_type(8)));
typedef _Float16 f16x4 __attribute__((ext_vector_type(4)));
typedef _Float16 f16x2 __attribute__((ext_vector_type(2)));

// ---------------------------------------------------------------------------
// Kernel 0: fp32 -> fp16 conversions (q,k,v, 4 weight mats, mask*(-1e9)*log2e)
// 2,097,152 threads: 4 mask elems, 2 q/k/v elems each; first 524,288 also 2 of
// each weight matrix.
// ---------------------------------------------------------------------------
__global__ __launch_bounds__(256) void convert_kernel(
    const float* __restrict__ q,  const float* __restrict__ k,  const float* __restrict__ v,
    const float* __restrict__ wq, const float* __restrict__ wk, const float* __restrict__ wv,
    const float* __restrict__ wd, const float* __restrict__ mask,
    _Float16* __restrict__ qx, _Float16* __restrict__ kx, _Float16* __restrict__ vx,
    _Float16* __restrict__ wqh, _Float16* __restrict__ wkh, _Float16* __restrict__ wvh,
    _Float16* __restrict__ wdh, _Float16* __restrict__ mlog)
{
    const size_t t = (size_t)blockIdx.x * 256 + threadIdx.x;
    {   // mask -> mask * (-1e9 * log2(e)), fp16 (overflow -> -inf, exp2 -> 0)
        f32x4 m = *(const f32x4*)(mask + t * 4);
        const float sc = -1.442695040888963e9f;
        f32x4 s = { m.x * sc, m.y * sc, m.z * sc, m.w * sc };
        *(f16x4*)(mlog + t * 4) = __builtin_convertvector(s, f16x4);
    }
    {   // q, k, v
        f32x2 a = *(const f32x2*)(q + t * 2);
        *(f16x2*)(qx + t * 2) = __builtin_convertvector(a, f16x2);
        f32x2 b = *(const f32x2*)(k + t * 2);
        *(f16x2*)(kx + t * 2) = __builtin_convertvector(b, f16x2);
        f32x2 c = *(const f32x2*)(v + t * 2);
        *(f16x2*)(vx + t * 2) = __builtin_convertvector(c, f16x2);
    }
    if (t < 524288) {   // 4 weight matrices, 1,048,576 elems each
        f32x2 a = *(const f32x2*)(wq + t * 2);
        *(f16x2*)(wqh + t * 2) = __builtin_convertvector(a, f16x2);
        f32x2 b = *(const f32x2*)(wk + t * 2);
        *(f16x2*)(wkh + t * 2) = __builtin_convertvector(b, f16x2);
        f32x2 c = *(const f32x2*)(wv + t * 2);
        *(f16x2*)(wvh + t * 2) = __builtin_convertvector(c, f16x2);
        f32x2 d = *(const f32x2*)(wd + t * 2);
        *(f16x2*)(wdh + t * 2) = __builtin_convertvector(d, f16x2);
    }
}

// ---------------------------------------------------------------------------
// GEMM core: C[m][n] = sum_k A[m][k] * W[n][k]  (both row-major, K-contiguous)
// 128x128 tile, BK=32, 256 threads (4 waves), each wave 64x64 via 4x4 tiles of
// v_mfma_f32_16x16x32_f16. LDS rows padded 32->40 elems for bank balance.
// ---------------------------------------------------------------------------
#define LDT 40

__device__ __forceinline__ void gemm_core_128(
    const _Float16* __restrict__ A, const _Float16* __restrict__ W,
    int m0, int n0, _Float16* sA, _Float16* sW, f32x4 acc[4][4])
{
    const int tid  = threadIdx.x;
    const int lane = tid & 63, wave = tid >> 6;
    const int wm = (wave & 1) * 64, wn = (wave >> 1) * 64;
    const int fl = lane & 15, fq = lane >> 4;

    for (int k0 = 0; k0 < 1024; k0 += 32) {
        __syncthreads();
#pragma unroll
        for (int i = 0; i < 2; i++) {
            int s = tid + i * 256;       // 512 slots: 128 rows x 4 chunks(16B)
            int row = s >> 2, ch = s & 3;
            *(f16x8*)&sA[row * LDT + ch * 8] =
                *(const f16x8*)(A + (size_t)(m0 + row) * 1024 + k0 + ch * 8);
            *(f16x8*)&sW[row * LDT + ch * 8] =
                *(const f16x8*)(W + (size_t)(n0 + row) * 1024 + k0 + ch * 8);
        }
        __syncthreads();
        f16x8 af[4], wf[4];
#pragma unroll
        for (int i = 0; i < 4; i++)
            af[i] = *(const f16x8*)&sA[(wm + i * 16 + fl) * LDT + fq * 8];
#pragma unroll
        for (int j = 0; j < 4; j++)
            wf[j] = *(const f16x8*)&sW[(wn + j * 16 + fl) * LDT + fq * 8];
#pragma unroll
        for (int i = 0; i < 4; i++)
#pragma unroll
            for (int j = 0; j < 4; j++)
                acc[i][j] = __builtin_amdgcn_mfma_f32_16x16x32_f16(
                    af[i], wf[j], acc[i][j], 0, 0, 0);
    }
}

// QKV projections. z=0: qh [b,h,s,64]; z=1: kh [b,h,s,64]; z=2: vt [b,h,64,s]
__global__ __launch_bounds__(256) void proj_gemm(
    const _Float16* __restrict__ qx, const _Float16* __restrict__ kx, const _Float16* __restrict__ vx,
    const _Float16* __restrict__ wqh, const _Float16* __restrict__ wkh, const _Float16* __restrict__ wvh,
    const float* __restrict__ bq, const float* __restrict__ bk, const float* __restrict__ bv,
    _Float16* __restrict__ qh, _Float16* __restrict__ kh, _Float16* __restrict__ vt)
{
    const _Float16* A; const _Float16* W; const float* bias; _Float16* outp; int transp;
    if (blockIdx.z == 0)      { A = qx; W = wqh; bias = bq; outp = qh; transp = 0; }
    else if (blockIdx.z == 1) { A = kx; W = wkh; bias = bk; outp = kh; transp = 0; }
    else                      { A = vx; W = wvh; bias = bv; outp = vt; transp = 1; }

    __shared__ _Float16 sA[128 * LDT];
    __shared__ _Float16 sW[128 * LDT];
    const int m0 = blockIdx.y * 128, n0 = blockIdx.x * 128;
    const int lane = threadIdx.x & 63, wave = threadIdx.x >> 6;
    const int wm = (wave & 1) * 64, wn = (wave >> 1) * 64;
    const int fl = lane & 15, fq = lane >> 4;

    f32x4 acc[4][4] = {};
    gemm_core_128(A, W, m0, n0, sA, sW, acc);

#pragma unroll
    for (int i = 0; i < 4; i++) {
#pragma unroll
        for (int j = 0; j < 4; j++) {
            int n = n0 + wn + j * 16 + fl;
            float bvv = bias[n];
            int h = n >> 6, d = n & 63;
#pragma unroll
            for (int r = 0; r < 4; r++) {
                int m = m0 + wm + i * 16 + fq * 4 + r;
                int b = m >> 11, s = m & 2047;
                float val = acc[i][j][r] + bvv;
                size_t addr;
                if (!transp) addr = (((size_t)(b * 16 + h) * 2048 + s) << 6) + d;
                else         addr = (((size_t)(b * 16 + h) * 64 + d) << 11) + s;
                outp[addr] = (_Float16)val;
            }
        }
    }
}

// Dense output projection: out = ob @ wd^T + bias, fp32 out
__global__ __launch_bounds__(256) void dense_gemm(
    const _Float16* __restrict__ A, const _Float16* __restrict__ W,
    const float* __restrict__ bias, float* __restrict__ outp)
{
    __shared__ _Float16 sA[128 * LDT];
    __shared__ _Float16 sW[128 * LDT];
    const int m0 = blockIdx.y * 128, n0 = blockIdx.x * 128;
    const int lane = threadIdx.x & 63, wave = threadIdx.x >> 6;
    const int wm = (wave & 1) * 64, wn = (wave >> 1) * 64;
    const int fl = lane & 15, fq = lane >> 4;

    f32x4 acc[4][4] = {};
    gemm_core_128(A, W, m0, n0, sA, sW, acc);

#pragma unroll
    for (int i = 0; i < 4; i++) {
#pragma unroll
        for (int j = 0; j < 4; j++) {
            int n = n0 + wn + j * 16 + fl;
            float bvv = bias[n];
#pragma unroll
            for (int r = 0; r < 4; r++) {
                int m = m0 + wm + i * 16 + fq * 4 + r;
                outp[(size_t)m * 1024 + n] = acc[i][j][r] + bvv;
            }
        }
    }
}

// ---------------------------------------------------------------------------
// Attention: per (b,h, 64-query block). 4 waves, wave w owns 16 queries.
// Pass A: l = sum exp2(dot*log2e/8 + mlog) over all 2048 keys (fixed m=0 —
//   logits ~N(0,1), no overflow risk; masked -> -inf -> 0).
// Pass B: recompute scores, P = exp2(...)*(1/l): write fp32 to d_out weights,
//   stage P in LDS (C-layout -> A-layout round trip), O += P @ V via MFMA.
// ---------------------------------------------------------------------------
#define LK 72     // sK row pad: 64+8
#define LV 136    // sV row pad: 128+8
#define LP 136

__global__ __launch_bounds__(256) void attn_kernel(
    const _Float16* __restrict__ qh, const _Float16* __restrict__ kh,
    const _Float16* __restrict__ vt, const _Float16* __restrict__ mlog,
    float* __restrict__ attw, _Float16* __restrict__ ob)
{
    __shared__ _Float16 sK[128 * LK];
    __shared__ _Float16 sV[64 * LV];
    __shared__ _Float16 sP[4][16 * LP];

    const int tid = threadIdx.x, lane = tid & 63, wave = tid >> 6;
    const int bh = blockIdx.y;
    const int b  = bh >> 4;
    const int q0 = blockIdx.x * 64 + wave * 16;   // first query of this wave
    const int fl = lane & 15, fq = lane >> 4;
    const _Float16* Kb = kh + (size_t)bh * 2048 * 64;
    const _Float16* Vb = vt + (size_t)bh * 64 * 2048;
    const _Float16* Mb = mlog + ((size_t)b * 2048 + q0) * 2048;
    const float SC = 0.18033688011112042f;        // log2(e)/8

    f16x8 qf[2];
    {
        const _Float16* Qb = qh + ((size_t)bh * 2048 + q0 + fl) * 64;
        qf[0] = *(const f16x8*)(Qb + fq * 8);
        qf[1] = *(const f16x8*)(Qb + 32 + fq * 8);
    }

    float lacc[4] = {0.f, 0.f, 0.f, 0.f};

    // ---- PASS A: denominator ----
    for (int kc = 0; kc < 16; kc++) {
        __syncthreads();
#pragma unroll
        for (int i = 0; i < 4; i++) {
            int s = tid + i * 256;                 // 1024 slots: 128 rows x 8
            int row = s >> 3, ch = s & 7;
            *(f16x8*)&sK[row * LK + ch * 8] =
                *(const f16x8*)(Kb + (size_t)(kc * 128 + row) * 64 + ch * 8);
        }
        __syncthreads();
#pragma unroll
        for (int nt = 0; nt < 8; nt++) {
            f16x8 kf0 = *(const f16x8*)&sK[(nt * 16 + fl) * LK + fq * 8];
            f16x8 kf1 = *(const f16x8*)&sK[(nt * 16 + fl) * LK + 32 + fq * 8];
            f32x4 sacc = {};
            sacc = __builtin_amdgcn_mfma_f32_16x16x32_f16(qf[0], kf0, sacc, 0, 0, 0);
            sacc = __builtin_amdgcn_mfma_f32_16x16x32_f16(qf[1], kf1, sacc, 0, 0, 0);
            int key = kc * 128 + nt * 16 + fl;
#pragma unroll
            for (int r = 0; r < 4; r++) {
                float mval = (float)Mb[(size_t)(fq * 4 + r) * 2048 + key];
                lacc[r] += exp2f(sacc[r] * SC + mval);
            }
        }
    }
    // reduce over the 16 column-lanes; store reciprocal
#pragma unroll
    for (int r = 0; r < 4; r++) {
        float x = lacc[r];
        x += __shfl_xor(x, 1);
        x += __shfl_xor(x, 2);
        x += __shfl_xor(x, 4);
        x += __shfl_xor(x, 8);
        lacc[r] = 1.0f / x;
    }

    f32x4 oacc[4] = {};

    // ---- PASS B: weights out + O = P@V ----
    for (int kc = 0; kc < 16; kc++) {
        __syncthreads();
#pragma unroll
        for (int i = 0; i < 4; i++) {
            int s = tid + i * 256;
            int row = s >> 3, ch = s & 7;
            *(f16x8*)&sK[row * LK + ch * 8] =
                *(const f16x8*)(Kb + (size_t)(kc * 128 + row) * 64 + ch * 8);
        }
#pragma unroll
        for (int i = 0; i < 4; i++) {
            int s = tid + i * 256;                 // 1024 slots: 64 rows x 16
            int row = s >> 4, ch = s & 15;
            *(f16x8*)&sV[row * LV + ch * 8] =
                *(const f16x8*)(Vb + (size_t)row * 2048 + kc * 128 + ch * 8);
        }
        __syncthreads();
#pragma unroll
        for (int nt = 0; nt < 8; nt++) {
            f16x8 kf0 = *(const f16x8*)&sK[(nt * 16 + fl) * LK + fq * 8];
            f16x8 kf1 = *(const f16x8*)&sK[(nt * 16 + fl) * LK + 32 + fq * 8];
            f32x4 sacc = {};
            sacc = __builtin_amdgcn_mfma_f32_16x16x32_f16(qf[0], kf0, sacc, 0, 0, 0);
            sacc = __builtin_amdgcn_mfma_f32_16x16x32_f16(qf[1], kf1, sacc, 0, 0, 0);
            int key = kc * 128 + nt * 16 + fl;
#pragma unroll
            for (int r = 0; r < 4; r++) {
                float mval = (float)Mb[(size_t)(fq * 4 + r) * 2048 + key];
                float p = exp2f(sacc[r] * SC + mval) * lacc[r];
                attw[((size_t)bh * 2048 + q0 + fq * 4 + r) * 2048 + key] = p;
                sP[wave][(fq * 4 + r) * LP + nt * 16 + fl] = (_Float16)p;
            }
        }
        __syncthreads();   // sP complete before A-fragment reads
#pragma unroll
        for (int km = 0; km < 4; km++) {
            f16x8 pf = *(const f16x8*)&sP[wave][fl * LP + km * 32 + fq * 8];
#pragma unroll
            for (int dt = 0; dt < 4; dt++) {
                f16x8 vf = *(const f16x8*)&sV[(dt * 16 + fl) * LV + km * 32 + fq * 8];
                oacc[dt] = __builtin_amdgcn_mfma_f32_16x16x32_f16(pf, vf, oacc[dt], 0, 0, 0);
            }
        }
    }

    // O -> ob [b][s][h*64+d] fp16
    const int h = bh & 15;
#pragma unroll
    for (int dt = 0; dt < 4; dt++) {
#pragma unroll
        for (int r = 0; r < 4; r++) {
            int qrow = q0 + fq * 4 + r;
            ob[((size_t)(b * 2048 + qrow)) * 1024 + h * 64 + dt * 16 + fl] =
                (_Float16)oacc[dt][r];
        }
    }
}

// ---------------------------------------------------------------------------
extern "C" void kernel_launch(void* const* d_in, const int* in_sizes, int n_in,
                              void* d_out, int out_size, void* d_ws, size_t ws_size,
                              hipStream_t stream)
{
    const float* q       = (const float*)d_in[0];
    const float* v       = (const float*)d_in[1];   // NOTE: v before k in input order
    const float* k       = (const float*)d_in[2];
    const float* mask    = (const float*)d_in[3];
    const float* wq_w    = (const float*)d_in[4];
    const float* wq_b    = (const float*)d_in[5];
    const float* wk_w    = (const float*)d_in[6];
    const float* wk_b    = (const float*)d_in[7];
    const float* wv_w    = (const float*)d_in[8];
    const float* wv_b    = (const float*)d_in[9];
    const float* dense_w = (const float*)d_in[10];
    const float* dense_b = (const float*)d_in[11];

    char* ws = (char*)d_ws;
    _Float16* qx   = (_Float16*)(ws + 0);
    _Float16* kx   = (_Float16*)(ws + 8388608);
    _Float16* vx   = (_Float16*)(ws + 16777216);
    _Float16* wqh  = (_Float16*)(ws + 25165824);
    _Float16* wkh  = (_Float16*)(ws + 27262976);
    _Float16* wvh  = (_Float16*)(ws + 29360128);
    _Float16* wdh  = (_Float16*)(ws + 31457280);
    _Float16* qhp  = (_Float16*)(ws + 33554432);
    _Float16* khp  = (_Float16*)(ws + 41943040);
    _Float16* vtp  = (_Float16*)(ws + 50331648);
    _Float16* obp  = (_Float16*)(ws + 58720256);
    _Float16* mlog = (_Float16*)(ws + 67108864);
    // total ws use: 83,886,080 bytes

    float* outp = (float*)d_out;
    float* attw = outp + (size_t)4194304;   // B*S*D fp32, then B*H*S*S fp32

    convert_kernel<<<8192, 256, 0, stream>>>(q, k, v, wq_w, wk_w, wv_w, dense_w,
                                             mask, qx, kx, vx, wqh, wkh, wvh, wdh, mlog);
    proj_gemm<<<dim3(8, 32, 3), 256, 0, stream>>>(qx, kx, vx, wqh, wkh, wvh,
                                                  wq_b, wk_b, wv_b, qhp, khp, vtp);
    attn_kernel<<<dim3(32, 32), 256, 0, stream>>>(qhp, khp, vtp, mlog, attw, obp);
    dense_gemm<<<dim3(8, 32), 256, 0, stream>>>(obp, wdh, dense_b, outp);
}